// Round 6
// baseline (158.629 us; speedup 1.0000x reference)
//
#include <hip/hip_runtime.h>
#include <math.h>

#define STEPS 3
#define BS 8
#define NCH 256
#define H 64
#define W 64
#define UP 8
#define OH (H*UP)
#define OW (W*UP)
#define GB 16              // channel groups (one partial buffer each)
#define CPB (NCH/GB)       // 16 channels per block
#define CPW (CPB/4)        // 4 channels per wave
#define CSTR 100           // LDS floats per channel record (3*32 used, pad->100)
#define DMAP_FLOATS (STEPS*BS*H*W)   // 98304

// ---- fused dmap: 4 waves/block share 4 rows, split 16 channels 4-way.
// Weights staged from ap into LDS (transpose in-flight; R3/R4-proven path —
// the R5 scalar-from-ap variant serialized on scalar-cache misses, reverted).
// GB=16 -> 2048 blocks (8/CU available), LDS 18.4 KB, launch_bounds(256,6)
// caps VGPR at 84 -> 6 resident blocks/CU = 24 waves/CU (R4 had 16).
__global__ __launch_bounds__(256, 6) void loca_dmap(
    const float* __restrict__ f_e,    // [BS, NCH, H, W]
    const float* __restrict__ ap,     // [STEPS, 27, BS, NCH] flattened
    const float* __restrict__ w_head, // [NCH]
    float* __restrict__ partial)      // [GB][STEPS][BS][H][W]
{
    __shared__ float wlds[CPB * CSTR];           // 1600 floats = 6.4 KB
    __shared__ float red[4][STEPS][256];         // 12 KB

    const int tid  = threadIdx.x;
    const int lane = tid & 63;
    const int wv   = tid >> 6;                   // wave 0..3
    const int rb   = blockIdx.x;                 // rowband 0..15
    const int b    = blockIdx.y;
    const int g    = blockIdx.z;                 // channel group 0..15
    const int row  = rb * 4 + (lane >> 4);
    const int xg   = lane & 15;
    const int C0   = g * CPB;

    // ---- stage weights: 16 ch x (3 steps x 28 floats) from ap, transposed.
    // record layout: wlds[lc*CSTR + i*32 + jj], jj<27 = taps, jj==27 = w_head.
    {
        const int lc_s = tid & 15;               // channel within block
        const int r0_s = tid >> 4;               // 0..15
        #pragma unroll
        for (int rr = 0; rr < 6; ++rr) {
            int rec = r0_s + rr * 16;            // 0..95
            if (rec < 3 * 28) {
                int i  = rec / 28;
                int jj = rec - i * 28;
                float v = (jj < 27)
                    ? ap[((size_t)(i * 27 + jj) * BS + b) * NCH + C0 + lc_s]
                    : w_head[C0 + lc_s];
                wlds[lc_s * CSTR + i * 32 + jj] = v;
            }
        }
    }
    __syncthreads();

    const float m_m1 = (row > 0)     ? 1.f : 0.f;
    const float m_p1 = (row < H - 1) ? 1.f : 0.f;
    const int r_m1 = row > 0     ? row - 1 : 0;
    const int r_p1 = row < H - 1 ? row + 1 : H - 1;

    const int cw = C0 + wv * CPW;                // this wave's first channel
    const float* fb = f_e + ((size_t)b * NCH + cw) * (H * W);

    float acc[STEPS][4] = {};

    // software pipeline: preload channel 0
    float4 nm = ((const float4*)(fb + r_m1 * W))[xg];
    float4 n0 = ((const float4*)(fb + row  * W))[xg];
    float4 np = ((const float4*)(fb + r_p1 * W))[xg];

    for (int cc = 0; cc < CPW; ++cc) {
        float4 vm = nm, v0 = n0, vp = np;
        if (cc + 1 < CPW) {
            const float* fc = fb + (cc + 1) * (H * W);
            nm = ((const float4*)(fc + r_m1 * W))[xg];
            n0 = ((const float4*)(fc + row  * W))[xg];
            np = ((const float4*)(fc + r_p1 * W))[xg];
        }
        vm.x *= m_m1; vm.y *= m_m1; vm.z *= m_m1; vm.w *= m_m1;
        vp.x *= m_p1; vp.y *= m_p1; vp.z *= m_p1; vp.w *= m_p1;

        // horizontal neighbors; 16-lane segment edges == image x-edges
        float Lm = __shfl_up(vm.w, 1);
        float L0 = __shfl_up(v0.w, 1);
        float Lp = __shfl_up(vp.w, 1);
        float Rm = __shfl_down(vm.x, 1);
        float R0 = __shfl_down(v0.x, 1);
        float Rp = __shfl_down(vp.x, 1);
        if (xg == 0)  { Lm = 0.f; L0 = 0.f; Lp = 0.f; }
        if (xg == 15) { Rm = 0.f; R0 = 0.f; Rp = 0.f; }

        float am[6]  = {Lm, vm.x, vm.y, vm.z, vm.w, Rm};
        float a0[6]  = {L0, v0.x, v0.y, v0.z, v0.w, R0};
        float apv[6] = {Lp, vp.x, vp.y, vp.z, vp.w, Rp};

        const int lc = wv * CPW + cc;            // local channel 0..15

        #pragma unroll
        for (int i = 0; i < STEPS; ++i) {
            // 7 x ds_read_b128 broadcast of this (channel, step)'s 28 floats
            union { float4 v4[7]; float f[28]; } qq;
            const float4* wp4 = (const float4*)(wlds + lc * CSTR + i * 32);
            #pragma unroll
            for (int q = 0; q < 7; ++q) qq.v4[q] = wp4[q];
            const float wh = qq.f[27];

            #pragma unroll
            for (int k = 0; k < 4; ++k) {
                float r_[3];
                #pragma unroll
                for (int o = 0; o < 3; ++o) {
                    float t = am[k] * qq.f[o * 9 + 0];
                    t = fmaf(am[k+1],  qq.f[o * 9 + 1], t);
                    t = fmaf(am[k+2],  qq.f[o * 9 + 2], t);
                    t = fmaf(a0[k],    qq.f[o * 9 + 3], t);
                    t = fmaf(a0[k+1],  qq.f[o * 9 + 4], t);
                    t = fmaf(a0[k+2],  qq.f[o * 9 + 5], t);
                    t = fmaf(apv[k],   qq.f[o * 9 + 6], t);
                    t = fmaf(apv[k+1], qq.f[o * 9 + 7], t);
                    t = fmaf(apv[k+2], qq.f[o * 9 + 8], t);
                    r_[o] = t;
                }
                // 2-exp differential softmax-weighted sum (exact rewrite):
                // sum_j p_j r_j = r0 + (E1*D1 + E2*D2) / (1 + E1 + E2)
                float D1 = r_[1] - r_[0];
                float D2 = r_[2] - r_[0];
                float E1 = __expf(D1);
                float E2 = __expf(D2);
                float den = 1.f + E1 + E2;
                float num = fmaf(E2, D2, E1 * D1);
#if __has_builtin(__builtin_amdgcn_rcpf)
                float redv = fmaf(num, __builtin_amdgcn_rcpf(den), r_[0]);
#else
                float redv = r_[0] + num / den;
#endif
                acc[i][k] = fmaf(wh, redv, acc[i][k]);
            }
        }
    }

    // cross-wave reduce in LDS, then one plain float4 store per (thread, step)
    const int px = (lane >> 4) * 64 + xg * 4;    // 0..255 within the rowband
    #pragma unroll
    for (int i = 0; i < STEPS; ++i) {
        float4 a; a.x = acc[i][0]; a.y = acc[i][1]; a.z = acc[i][2]; a.w = acc[i][3];
        *(float4*)&red[wv][i][px] = a;
    }
    __syncthreads();
    #pragma unroll
    for (int i = 0; i < STEPS; ++i) {
        float4 s0 = *(const float4*)&red[0][i][px];
        float4 s1 = *(const float4*)&red[1][i][px];
        float4 s2 = *(const float4*)&red[2][i][px];
        float4 s3 = *(const float4*)&red[3][i][px];
        float4 s;
        s.x = (s0.x + s1.x) + (s2.x + s3.x);
        s.y = (s0.y + s1.y) + (s2.y + s3.y);
        s.z = (s0.z + s1.z) + (s2.z + s3.z);
        s.w = (s0.w + s1.w) + (s2.w + s3.w);
        *(float4*)&partial[(size_t)g * DMAP_FLOATS + ((size_t)(i * BS + b)) * (H * W)
                           + row * W + xg * 4] = s;
    }
}

// ---- fused group-reduce + bias + relu + bilinear 8x upsample --------------
// One block per (input row k, ib): stage rows k-1,k,k+1 (clamped) summed over
// GB groups into LDS, then emit output rows 8k..8k+7 (512 px each).
__global__ __launch_bounds__(256) void loca_upred(
    const float* __restrict__ partial,   // [GB][STEPS*BS][H][W]
    const float* __restrict__ b_head,
    float* __restrict__ out)             // [STEPS*BS][OH][OW]
{
    __shared__ float sm[3][W];           // 3 staged input rows

    const int k  = blockIdx.x;           // input row 0..63
    const int ib = blockIdx.y;           // (i*BS+b) 0..23
    const int t  = threadIdx.x;

    if (t < 3 * W) {
        const int r  = t >> 6;           // 0..2
        const int x  = t & (W - 1);
        int ry = k - 1 + r;
        ry = min(max(ry, 0), H - 1);
        const float* p = partial + (size_t)ib * (H * W) + (size_t)ry * W + x;
        float s = 0.f;
        #pragma unroll
        for (int g = 0; g < GB; ++g) s += p[(size_t)g * DMAP_FLOATS];
        sm[r][x] = fmaxf(s + b_head[0], 0.f);
    }
    __syncthreads();

    float* obase = out + (size_t)ib * (OH * OW) + (size_t)(UP * k) * OW;
    #pragma unroll
    for (int rep = 0; rep < 4; ++rep) {
        const int u  = rep * 256 + t;    // 0..1023 float4 units in the 8-row band
        const int ry = u >> 7;           // output row within band 0..7
        const int gx = u & 127;          // float4 column 0..127

        float yin = (UP * k + ry + 0.5f) * 0.125f - 0.5f;
        float fy0 = floorf(yin);
        int   iy  = (int)fy0;
        float fy  = yin - fy0;
        // iy in {k-1, k}  ->  staged row index in {0,1}; +1 below
        const float* r0 = sm[iy - (k - 1)];
        const float* r1 = sm[iy - (k - 1) + 1];

        float4 o;
        float* op = &o.x;
        #pragma unroll
        for (int j = 0; j < 4; ++j) {
            int X = gx * 4 + j;
            float xin = (X + 0.5f) * 0.125f - 0.5f;
            float fx0 = floorf(xin);
            int   ix  = (int)fx0;
            float fx  = xin - fx0;
            int x0c = min(max(ix, 0), W - 1);
            int x1c = min(max(ix + 1, 0), W - 1);
            float a00 = r0[x0c], a01 = r0[x1c];
            float a10 = r1[x0c], a11 = r1[x1c];
            float v0 = a00 + fx * (a01 - a00);
            float v1 = a10 + fx * (a11 - a10);
            op[j] = v0 + fy * (v1 - v0);
        }
        ((float4*)obase)[u] = o;
    }
}

extern "C" void kernel_launch(void* const* d_in, const int* in_sizes, int n_in,
                              void* d_out, int out_size, void* d_ws, size_t ws_size,
                              hipStream_t stream) {
    const float* f_e    = (const float*)d_in[0];
    const float* ap     = (const float*)d_in[1];
    const float* w_head = (const float*)d_in[2];
    const float* b_head = (const float*)d_in[3];
    float* out     = (float*)d_out;
    float* partial = (float*)d_ws;                   // GB*98304 floats (6 MB)

    dim3 g1(16, BS, GB);   // 16 rowbands x 8 b x 16 groups = 2048 blocks
    loca_dmap<<<g1, 256, 0, stream>>>(f_e, ap, w_head, partial);

    dim3 g2(H, STEPS * BS);  // 64 input rows x 24 planes = 1536 blocks
    loca_upred<<<g2, 256, 0, stream>>>(partial, b_head, out);
}

// Round 7
// 111.853 us; speedup vs baseline: 1.4182x; 1.4182x over previous
//
#include <hip/hip_runtime.h>
#include <math.h>

#define STEPS 3
#define BS 8
#define NCH 256
#define H 64
#define W 64
#define UP 8
#define OH (H*UP)
#define OW (W*UP)
#define GB 16              // channel groups (one partial buffer each)
#define CPB (NCH/GB)       // 16 channels per block
#define CPW (CPB/4)        // 4 channels per wave
#define CSTR 100           // LDS floats per channel record (3*32 used, pad->100)
#define DMAP_FLOATS (STEPS*BS*H*W)   // 98304

// ---- fused dmap: 4 waves/block share 4 rows, split 16 channels 4-way.
// Weights staged from ap into LDS (R3/R4-proven path). GB=16 -> 2048 blocks
// (8/CU available), LDS 18.4 KB (8/CU allowed). NO min-waves clamp: R5/R6's
// launch_bounds(256,6) forced VGPR 100->40 and spilled ~50-110 MB to scratch
// (WRITE_SIZE smoking gun). Natural VGPR ~100 -> 5 blocks/CU = 20 waves/CU.
__global__ __launch_bounds__(256) void loca_dmap(
    const float* __restrict__ f_e,    // [BS, NCH, H, W]
    const float* __restrict__ ap,     // [STEPS, 27, BS, NCH] flattened
    const float* __restrict__ w_head, // [NCH]
    float* __restrict__ partial)      // [GB][STEPS][BS][H][W]
{
    __shared__ float wlds[CPB * CSTR];           // 1600 floats = 6.4 KB
    __shared__ float red[4][STEPS][256];         // 12 KB

    const int tid  = threadIdx.x;
    const int lane = tid & 63;
    const int wv   = tid >> 6;                   // wave 0..3
    const int rb   = blockIdx.x;                 // rowband 0..15
    const int b    = blockIdx.y;
    const int g    = blockIdx.z;                 // channel group 0..15
    const int row  = rb * 4 + (lane >> 4);
    const int xg   = lane & 15;
    const int C0   = g * CPB;

    // ---- stage weights: 16 ch x (3 steps x 28 floats) from ap, transposed.
    // record layout: wlds[lc*CSTR + i*32 + jj], jj<27 = taps, jj==27 = w_head.
    {
        const int lc_s = tid & 15;               // channel within block
        const int r0_s = tid >> 4;               // 0..15
        #pragma unroll
        for (int rr = 0; rr < 6; ++rr) {
            int rec = r0_s + rr * 16;            // 0..95
            if (rec < 3 * 28) {
                int i  = rec / 28;
                int jj = rec - i * 28;
                float v = (jj < 27)
                    ? ap[((size_t)(i * 27 + jj) * BS + b) * NCH + C0 + lc_s]
                    : w_head[C0 + lc_s];
                wlds[lc_s * CSTR + i * 32 + jj] = v;
            }
        }
    }
    __syncthreads();

    const float m_m1 = (row > 0)     ? 1.f : 0.f;
    const float m_p1 = (row < H - 1) ? 1.f : 0.f;
    const int r_m1 = row > 0     ? row - 1 : 0;
    const int r_p1 = row < H - 1 ? row + 1 : H - 1;

    const int cw = C0 + wv * CPW;                // this wave's first channel
    const float* fb = f_e + ((size_t)b * NCH + cw) * (H * W);

    float acc[STEPS][4] = {};

    // software pipeline: preload channel 0
    float4 nm = ((const float4*)(fb + r_m1 * W))[xg];
    float4 n0 = ((const float4*)(fb + row  * W))[xg];
    float4 np = ((const float4*)(fb + r_p1 * W))[xg];

    for (int cc = 0; cc < CPW; ++cc) {
        float4 vm = nm, v0 = n0, vp = np;
        if (cc + 1 < CPW) {
            const float* fc = fb + (cc + 1) * (H * W);
            nm = ((const float4*)(fc + r_m1 * W))[xg];
            n0 = ((const float4*)(fc + row  * W))[xg];
            np = ((const float4*)(fc + r_p1 * W))[xg];
        }
        vm.x *= m_m1; vm.y *= m_m1; vm.z *= m_m1; vm.w *= m_m1;
        vp.x *= m_p1; vp.y *= m_p1; vp.z *= m_p1; vp.w *= m_p1;

        // horizontal neighbors; 16-lane segment edges == image x-edges
        float Lm = __shfl_up(vm.w, 1);
        float L0 = __shfl_up(v0.w, 1);
        float Lp = __shfl_up(vp.w, 1);
        float Rm = __shfl_down(vm.x, 1);
        float R0 = __shfl_down(v0.x, 1);
        float Rp = __shfl_down(vp.x, 1);
        if (xg == 0)  { Lm = 0.f; L0 = 0.f; Lp = 0.f; }
        if (xg == 15) { Rm = 0.f; R0 = 0.f; Rp = 0.f; }

        float am[6]  = {Lm, vm.x, vm.y, vm.z, vm.w, Rm};
        float a0[6]  = {L0, v0.x, v0.y, v0.z, v0.w, R0};
        float apv[6] = {Lp, vp.x, vp.y, vp.z, vp.w, Rp};

        const int lc = wv * CPW + cc;            // local channel 0..15

        #pragma unroll
        for (int i = 0; i < STEPS; ++i) {
            // 7 x ds_read_b128 broadcast of this (channel, step)'s 28 floats
            union { float4 v4[7]; float f[28]; } qq;
            const float4* wp4 = (const float4*)(wlds + lc * CSTR + i * 32);
            #pragma unroll
            for (int q = 0; q < 7; ++q) qq.v4[q] = wp4[q];
            const float wh = qq.f[27];

            #pragma unroll
            for (int k = 0; k < 4; ++k) {
                float r_[3];
                #pragma unroll
                for (int o = 0; o < 3; ++o) {
                    float t = am[k] * qq.f[o * 9 + 0];
                    t = fmaf(am[k+1],  qq.f[o * 9 + 1], t);
                    t = fmaf(am[k+2],  qq.f[o * 9 + 2], t);
                    t = fmaf(a0[k],    qq.f[o * 9 + 3], t);
                    t = fmaf(a0[k+1],  qq.f[o * 9 + 4], t);
                    t = fmaf(a0[k+2],  qq.f[o * 9 + 5], t);
                    t = fmaf(apv[k],   qq.f[o * 9 + 6], t);
                    t = fmaf(apv[k+1], qq.f[o * 9 + 7], t);
                    t = fmaf(apv[k+2], qq.f[o * 9 + 8], t);
                    r_[o] = t;
                }
                // 2-exp differential softmax-weighted sum (exact rewrite):
                // sum_j p_j r_j = r0 + (E1*D1 + E2*D2) / (1 + E1 + E2)
                float D1 = r_[1] - r_[0];
                float D2 = r_[2] - r_[0];
                float E1 = __expf(D1);
                float E2 = __expf(D2);
                float den = 1.f + E1 + E2;
                float num = fmaf(E2, D2, E1 * D1);
#if __has_builtin(__builtin_amdgcn_rcpf)
                float redv = fmaf(num, __builtin_amdgcn_rcpf(den), r_[0]);
#else
                float redv = r_[0] + num / den;
#endif
                acc[i][k] = fmaf(wh, redv, acc[i][k]);
            }
        }
    }

    // cross-wave reduce in LDS, then one plain float4 store per (thread, step)
    const int px = (lane >> 4) * 64 + xg * 4;    // 0..255 within the rowband
    #pragma unroll
    for (int i = 0; i < STEPS; ++i) {
        float4 a; a.x = acc[i][0]; a.y = acc[i][1]; a.z = acc[i][2]; a.w = acc[i][3];
        *(float4*)&red[wv][i][px] = a;
    }
    __syncthreads();
    #pragma unroll
    for (int i = 0; i < STEPS; ++i) {
        float4 s0 = *(const float4*)&red[0][i][px];
        float4 s1 = *(const float4*)&red[1][i][px];
        float4 s2 = *(const float4*)&red[2][i][px];
        float4 s3 = *(const float4*)&red[3][i][px];
        float4 s;
        s.x = (s0.x + s1.x) + (s2.x + s3.x);
        s.y = (s0.y + s1.y) + (s2.y + s3.y);
        s.z = (s0.z + s1.z) + (s2.z + s3.z);
        s.w = (s0.w + s1.w) + (s2.w + s3.w);
        *(float4*)&partial[(size_t)g * DMAP_FLOATS + ((size_t)(i * BS + b)) * (H * W)
                           + row * W + xg * 4] = s;
    }
}

// ---- fused group-reduce + bias + relu + bilinear 8x upsample --------------
// One block per (input row k, ib): stage rows k-1,k,k+1 (clamped) summed over
// GB groups into LDS, then emit output rows 8k..8k+7 (512 px each).
__global__ __launch_bounds__(256) void loca_upred(
    const float* __restrict__ partial,   // [GB][STEPS*BS][H][W]
    const float* __restrict__ b_head,
    float* __restrict__ out)             // [STEPS*BS][OH][OW]
{
    __shared__ float sm[3][W];           // 3 staged input rows

    const int k  = blockIdx.x;           // input row 0..63
    const int ib = blockIdx.y;           // (i*BS+b) 0..23
    const int t  = threadIdx.x;

    if (t < 3 * W) {
        const int r  = t >> 6;           // 0..2
        const int x  = t & (W - 1);
        int ry = k - 1 + r;
        ry = min(max(ry, 0), H - 1);
        const float* p = partial + (size_t)ib * (H * W) + (size_t)ry * W + x;
        float s = 0.f;
        #pragma unroll
        for (int g = 0; g < GB; ++g) s += p[(size_t)g * DMAP_FLOATS];
        sm[r][x] = fmaxf(s + b_head[0], 0.f);
    }
    __syncthreads();

    float* obase = out + (size_t)ib * (OH * OW) + (size_t)(UP * k) * OW;
    #pragma unroll
    for (int rep = 0; rep < 4; ++rep) {
        const int u  = rep * 256 + t;    // 0..1023 float4 units in the 8-row band
        const int ry = u >> 7;           // output row within band 0..7
        const int gx = u & 127;          // float4 column 0..127

        float yin = (UP * k + ry + 0.5f) * 0.125f - 0.5f;
        float fy0 = floorf(yin);
        int   iy  = (int)fy0;
        float fy  = yin - fy0;
        // iy in {k-1, k}  ->  staged row index in {0,1}; +1 below
        const float* r0 = sm[iy - (k - 1)];
        const float* r1 = sm[iy - (k - 1) + 1];

        float4 o;
        float* op = &o.x;
        #pragma unroll
        for (int j = 0; j < 4; ++j) {
            int X = gx * 4 + j;
            float xin = (X + 0.5f) * 0.125f - 0.5f;
            float fx0 = floorf(xin);
            int   ix  = (int)fx0;
            float fx  = xin - fx0;
            int x0c = min(max(ix, 0), W - 1);
            int x1c = min(max(ix + 1, 0), W - 1);
            float a00 = r0[x0c], a01 = r0[x1c];
            float a10 = r1[x0c], a11 = r1[x1c];
            float v0 = a00 + fx * (a01 - a00);
            float v1 = a10 + fx * (a11 - a10);
            op[j] = v0 + fy * (v1 - v0);
        }
        ((float4*)obase)[u] = o;
    }
}

extern "C" void kernel_launch(void* const* d_in, const int* in_sizes, int n_in,
                              void* d_out, int out_size, void* d_ws, size_t ws_size,
                              hipStream_t stream) {
    const float* f_e    = (const float*)d_in[0];
    const float* ap     = (const float*)d_in[1];
    const float* w_head = (const float*)d_in[2];
    const float* b_head = (const float*)d_in[3];
    float* out     = (float*)d_out;
    float* partial = (float*)d_ws;                   // GB*98304 floats (6 MB)

    dim3 g1(16, BS, GB);   // 16 rowbands x 8 b x 16 groups = 2048 blocks
    loca_dmap<<<g1, 256, 0, stream>>>(f_e, ap, w_head, partial);

    dim3 g2(H, STEPS * BS);  // 64 input rows x 24 planes = 1536 blocks
    loca_upred<<<g2, 256, 0, stream>>>(partial, b_head, out);
}